// Round 1
// 1132.114 us; speedup vs baseline: 1.5291x; 1.5291x over previous
//
#include <hip/hip_runtime.h>
#include <hip/hip_bf16.h>
#include <cstdint>

typedef unsigned short u16;
typedef unsigned int u32;
typedef __attribute__((ext_vector_type(8))) short short8;   // 8 x bf16 (4 VGPRs)
typedef __attribute__((ext_vector_type(4))) float f32x4;    // MFMA accumulator

#define TID ((int)threadIdx.x)

// bf16 (as ushort bits) -> f32
__device__ __forceinline__ float b2f(u16 u) { return __uint_as_float(((u32)u) << 16); }
// f32 -> bf16 (RNE)
__device__ __forceinline__ u16 f2b(float f) {
    u32 u = __float_as_uint(f);
    u += 0x7fffu + ((u >> 16) & 1u);
    return (u16)(u >> 16);
}
__device__ __forceinline__ float2 upk(u32 u) {
    float2 r;
    r.x = __uint_as_float(u << 16);
    r.y = __uint_as_float(u & 0xffff0000u);
    return r;
}
__device__ __forceinline__ float silu_f(float x) { return x / (1.f + __expf(-x)); }

// dtype-adaptive scalar load (wave-uniform bf flag)
__device__ __forceinline__ float ldx(const void* p, size_t i, bool bf) {
    float v;
    if (bf) v = b2f(((const u16*)p)[i]);
    else    v = ((const float*)p)[i];
    return v;
}

// ---------------- constants ----------------
#define BB 32
#define NN 128
#define DD 256
#define MM 4096
#define HH 1024
#define BN (BB * NN)   // 4096 rows

// workspace layout (floats)
#define O_FLAG 0
#define O_H2   8
#define O_S    (O_H2 + 256)                // 264
#define O_FAT  (O_S + BN)                  // 4360
#define O_WQT  (O_FAT + BN * DD)
#define O_WGT  (O_WQT + 256 * 256)
#define O_WF0T (O_WGT + 512 * 256)
#define O_WF1T (O_WF0T + 512 * 1024)
#define O_SNA  (O_WF1T + 1024 * 256)
#define O_SNF  (O_SNA + BN * DD)
#define O_Q    (O_SNF + BN * DD)           // now holds q as bf16 (u16), uses half the region
#define O_H    (O_Q + BN * DD)
// total = O_H + BN*HH ≈ 9.38M floats (~37.5 MB) — unchanged

// ---------------- K0: dtype probe ----------------
__global__ void probe_dtype(const void* lnAw, int* flag) {
    u32 bits = *(const u32*)lnAw;
    *flag = ((bits & 0xFFFFu) == 0x3F80u) ? 1 : 0;
}

// ---------------- K1: time-dependent tiny MLP (h2 for 4 heads) ----------------
__global__ __launch_bounds__(256) void tdw_mlp(
    const void* t,
    const void* qw0, const void* qb0, const void* qw1, const void* qb1,
    const void* gw0, const void* gb0, const void* gw1, const void* gb1,
    const void* f0w0, const void* f0b0, const void* f0w1, const void* f0b1,
    const void* f1w0, const void* f1b0, const void* f1w1, const void* f1b1,
    float* h2out, const int* flagp)
{
    __shared__ float emb[257];
    __shared__ float h1s[256];
    bool bf = (*flagp != 0);
    float tv = ldx(t, 0, bf);
    const float c = -9.210340371976184f / 128.f;  // -ln(10000)/N_FREQ
    for (int i = TID; i < 257; i += 256) {
        float val;
        if (i == 0) val = tv;
        else if (i <= 128) val = sinf(c * (float)(i - 1) * tv);
        else val = cosf(c * (float)(i - 129) * tv);
        emb[i] = val;
    }
    __syncthreads();
    int head = TID >> 6, o = TID & 63;
    const void* w0s[4] = {qw0, gw0, f0w0, f1w0};
    const void* b0s[4] = {qb0, gb0, f0b0, f1b0};
    const void* w1s[4] = {qw1, gw1, f0w1, f1w1};
    const void* b1s[4] = {qb1, gb1, f0b1, f1b1};
    float acc = ldx(b0s[head], o, bf);
    if (bf) {
        const u16* w0 = (const u16*)w0s[head];
        for (int j = 0; j < 257; j++) acc += b2f(w0[o * 257 + j]) * emb[j];
    } else {
        const float* w0 = (const float*)w0s[head];
        for (int j = 0; j < 257; j++) acc += w0[o * 257 + j] * emb[j];
    }
    h1s[TID] = silu_f(acc);
    __syncthreads();
    float acc2 = ldx(b1s[head], o, bf);
    if (bf) {
        const u16* w1 = (const u16*)w1s[head];
        for (int j = 0; j < 64; j++) acc2 += b2f(w1[o * 64 + j]) * h1s[head * 64 + j];
    } else {
        const float* w1 = (const float*)w1s[head];
        for (int j = 0; j < 64; j++) acc2 += w1[o * 64 + j] * h1s[head * 64 + j];
    }
    h2out[TID] = silu_f(acc2);
}

// ---------------- K2: W = wp @ h2 + bp, written TRANSPOSED: WT[d*dout+o] ----------------
__global__ __launch_bounds__(256) void tdw_proj(
    const void* __restrict__ wp, const void* __restrict__ bp,
    const float* __restrict__ h2, float* __restrict__ WT,
    int dout_shift, int din, const int* flagp)
{
    __shared__ float h2s[64];
    bool bf = (*flagp != 0);
    if (TID < 64) h2s[TID] = h2[TID];
    __syncthreads();
    int j = blockIdx.x * 256 + TID;          // j = d*dout + o (coalesced write)
    int d = j >> dout_shift;
    int o = j & ((1 << dout_shift) - 1);
    long i = (long)o * din + d;              // original row index
    float acc;
    if (bf) acc = b2f(((const u16*)bp)[i]);
    else    acc = ((const float*)bp)[i];
    if (bf) {
        const uint4* row = (const uint4*)((const u16*)wp + i * 64);
#pragma unroll
        for (int r = 0; r < 8; r++) {
            uint4 u = row[r];
            float2 p;
            p = upk(u.x); acc += p.x * h2s[r * 8 + 0] + p.y * h2s[r * 8 + 1];
            p = upk(u.y); acc += p.x * h2s[r * 8 + 2] + p.y * h2s[r * 8 + 3];
            p = upk(u.z); acc += p.x * h2s[r * 8 + 4] + p.y * h2s[r * 8 + 5];
            p = upk(u.w); acc += p.x * h2s[r * 8 + 6] + p.y * h2s[r * 8 + 7];
        }
    } else {
        const float4* row = (const float4*)((const float*)wp + i * 64);
#pragma unroll
        for (int r = 0; r < 16; r++) {
            float4 u = row[r];
            acc += u.x * h2s[r * 4 + 0] + u.y * h2s[r * 4 + 1]
                 + u.z * h2s[r * 4 + 2] + u.w * h2s[r * 4 + 3];
        }
    }
    WT[j] = acc;
}

// ---------------- K3: LayerNorm (both A and F affine variants) ----------------
__global__ __launch_bounds__(256) void layernorm_k(
    const void* __restrict__ slots,
    const void* lnAw, const void* lnAb, const void* lnFw, const void* lnFb,
    float* __restrict__ snA, float* __restrict__ snF, const int* flagp)
{
    int bn = blockIdx.x;
    bool bf = (*flagp != 0);
    float x;
    if (bf) x = b2f(((const u16*)slots)[(size_t)bn * DD + TID]);
    else    x = ((const float*)slots)[(size_t)bn * DD + TID];
    float s1 = x, s2 = x * x;
    for (int off = 32; off; off >>= 1) {
        s1 += __shfl_down(s1, off, 64);
        s2 += __shfl_down(s2, off, 64);
    }
    __shared__ float r1[4], r2[4];
    __shared__ float mu_s, rs_s;
    if ((TID & 63) == 0) { r1[TID >> 6] = s1; r2[TID >> 6] = s2; }
    __syncthreads();
    if (TID == 0) {
        float a = r1[0] + r1[1] + r1[2] + r1[3];
        float b = r2[0] + r2[1] + r2[2] + r2[3];
        float mu = a * (1.f / 256.f);
        float var = b * (1.f / 256.f) - mu * mu;
        mu_s = mu;
        rs_s = rsqrtf(var + 1e-5f);
    }
    __syncthreads();
    float xh = (x - mu_s) * rs_s;
    snA[(size_t)bn * DD + TID] = xh * ldx(lnAw, TID, bf) + ldx(lnAb, TID, bf);
    snF[(size_t)bn * DD + TID] = xh * ldx(lnFw, TID, bf) + ldx(lnFb, TID, bf);
}

// ---------------- K4: q = snA @ WqT, output bf16 (for MFMA attention) ----------------
__global__ __launch_bounds__(256) void qproj(
    const float* __restrict__ snA, const float* __restrict__ WqT, u16* __restrict__ qb)
{
    int rb = blockIdx.x;
    __shared__ float sn[8][256];
    for (int idx = TID; idx < 2048; idx += 256)
        sn[idx >> 8][idx & 255] = snA[(size_t)rb * 2048 + idx];
    __syncthreads();
    float acc[8] = {0, 0, 0, 0, 0, 0, 0, 0};
    for (int d = 0; d < 256; d++) {
        float w = WqT[d * 256 + TID];
#pragma unroll
        for (int r = 0; r < 8; r++) acc[r] += sn[r][d] * w;
    }
    for (int r = 0; r < 8; r++) qb[(size_t)(rb * 8 + r) * 256 + TID] = f2b(acc[r]);
}

// ---------------- K5: MFMA attention ----------------
// Block = (m-tile of 128 feats, batch b). 4 waves, 256 threads.
// Wave w owns 32 feat-columns [32w,32w+32) for QK+softmax, and dv-slice [64w,64w+64) for PV.
// LDS: qb[128n][64d] + kb[128m][64d] (bf16, XOR-swizzled), overlaid by att[128n][128m] after QK.
//      vt[dv][m] (stride 40 u16) holds the transposed 32-m v slab for PV B-fragments.
__global__ __launch_bounds__(256, 2) void attn_mfma(
    const u16* __restrict__ qbG,       // [B*128][256] bf16
    const void* __restrict__ k, const void* __restrict__ v,
    float* __restrict__ fat, float* __restrict__ S, const int* flagp)
{
    const int b = blockIdx.y;
    const int m0 = blockIdx.x * 128;
    const bool bf = (*flagp != 0);
    const int t = TID;
    const int l = t & 63, w = t >> 6;
    const int lg = l >> 4;       // lane group 0..3
    const int ll = l & 15;

    __shared__ alignas(16) u16 AB[128 * 128];   // 32 KB: qb(8K u16) + kb(8K u16), reused as att(16K u16)
    __shared__ alignas(16) u16 vt[256 * 40];    // 20 KB

    u16* qb = AB;            // [n][64]   byte = n*128 + (doff ^ ((n&7)<<4))
    u16* kb = AB + 8192;     // [mm][64]  byte = mm*128 + (doff ^ ((mm&7)<<4))

    f32x4 acc[2][8];
#pragma unroll
    for (int s = 0; s < 2; s++)
#pragma unroll
        for (int nt = 0; nt < 8; nt++) acc[s][nt] = {0.f, 0.f, 0.f, 0.f};

    // ---------- QK^T: acc[s][nt] = q[16nt..][d] . k[32w+16s..][d], d-chunks of 64 ----------
    for (int dc = 0; dc < 4; dc++) {
        {   // stage q chunk (bf16 source): 4096 u32
            const u32* qg = (const u32*)qbG + (size_t)b * 128 * 128 + dc * 32;
#pragma unroll
            for (int i = 0; i < 16; i++) {
                int fid = i * 256 + t;
                int n = fid >> 5, dp = fid & 31;
                u32 val = qg[n * 128 + dp];
                *(u32*)((char*)qb + n * 128 + ((dp * 4) ^ ((n & 7) << 4))) = val;
            }
        }
        if (bf) {   // stage k chunk, bf16 wire
            const u32* kg = (const u32*)k + ((size_t)(b * MM + m0)) * 128 + dc * 32;
#pragma unroll
            for (int i = 0; i < 16; i++) {
                int fid = i * 256 + t;
                int mm = fid >> 5, dp = fid & 31;
                u32 val = kg[(size_t)mm * 128 + dp];
                *(u32*)((char*)kb + mm * 128 + ((dp * 4) ^ ((mm & 7) << 4))) = val;
            }
        } else {    // fp32 wire: convert on the fly
            const float4* kg = (const float4*)k + ((size_t)(b * MM + m0)) * 64 + dc * 16;
#pragma unroll
            for (int i = 0; i < 8; i++) {
                int fid = i * 256 + t;
                int mm = fid >> 4, q4 = fid & 15;
                float4 f = kg[(size_t)mm * 64 + q4];
                u32 p0 = ((u32)f2b(f.x)) | ((u32)f2b(f.y) << 16);
                u32 p1 = ((u32)f2b(f.z)) | ((u32)f2b(f.w) << 16);
                char* base = (char*)kb + mm * 128;
                *(u32*)(base + (((q4 * 8) + 0) ^ ((mm & 7) << 4))) = p0;
                *(u32*)(base + (((q4 * 8) + 4) ^ ((mm & 7) << 4))) = p1;
            }
        }
        __syncthreads();
#pragma unroll
        for (int ds = 0; ds < 2; ds++) {
            int doff = ds * 64 + lg * 16;
            short8 bfr[2];
#pragma unroll
            for (int s = 0; s < 2; s++) {
                int mm = w * 32 + s * 16 + ll;
                bfr[s] = *(const short8*)((char*)kb + mm * 128 + (doff ^ ((mm & 7) << 4)));
            }
#pragma unroll
            for (int nt = 0; nt < 8; nt++) {
                int n = nt * 16 + ll;
                short8 af = *(const short8*)((char*)qb + n * 128 + (doff ^ ((n & 7) << 4)));
                acc[0][nt] = __builtin_amdgcn_mfma_f32_16x16x32_bf16(af, bfr[0], acc[0][nt], 0, 0, 0);
                acc[1][nt] = __builtin_amdgcn_mfma_f32_16x16x32_bf16(af, bfr[1], acc[1][nt], 0, 0, 0);
            }
        }
        __syncthreads();
    }

    // ---------- softmax over slots (n), per column m; fully in-register ----------
    // D layout: value (s,nt,r) is at n = 16nt + 4lg + r, mcol = 32w + 16s + ll.
    // A column's 128 n live in lanes {ll, ll+16, ll+32, ll+48} x 4 regs x 8 ntiles.
    const float scale = 0.0625f;
#pragma unroll
    for (int s = 0; s < 2; s++) {
        float cm = -1e30f;
#pragma unroll
        for (int nt = 0; nt < 8; nt++)
#pragma unroll
            for (int r = 0; r < 4; r++) cm = fmaxf(cm, acc[s][nt][r]);
        cm = fmaxf(cm, __shfl_xor(cm, 16));
        cm = fmaxf(cm, __shfl_xor(cm, 32));
        float cs = 0.f;
#pragma unroll
        for (int nt = 0; nt < 8; nt++)
#pragma unroll
            for (int r = 0; r < 4; r++) {
                float ev = __expf((acc[s][nt][r] - cm) * scale);
                acc[s][nt][r] = ev;
                cs += ev;
            }
        cs += __shfl_xor(cs, 16);
        cs += __shfl_xor(cs, 32);
        float inv = 1.f / cs;
#pragma unroll
        for (int nt = 0; nt < 8; nt++)
#pragma unroll
            for (int r = 0; r < 4; r++) acc[s][nt][r] *= inv;
    }

    // ---------- att -> LDS (bf16, swizzled) + S row-sum partials ----------
    u16* att = AB;   // [n][128] byte = n*256 + ((mw*2) ^ ((n&7)<<4))
#pragma unroll
    for (int s = 0; s < 2; s++)
#pragma unroll
        for (int nt = 0; nt < 8; nt++)
#pragma unroll
            for (int r = 0; r < 4; r++) {
                int n = nt * 16 + lg * 4 + r;
                int mw = w * 32 + s * 16 + ll;
                *(u16*)((char*)att + n * 256 + ((mw * 2) ^ ((n & 7) << 4))) = f2b(acc[s][nt][r]);
            }
    // S[n] += sum over this block's 128 feats (butterfly over the 16 ll-lanes)
#pragma unroll
    for (int nt = 0; nt < 8; nt++)
#pragma unroll
        for (int r = 0; r < 4; r++) {
            float vsum = acc[0][nt][r] + acc[1][nt][r];
            vsum += __shfl_xor(vsum, 1);
            vsum += __shfl_xor(vsum, 2);
            vsum += __shfl_xor(vsum, 4);
            vsum += __shfl_xor(vsum, 8);
            if (ll == 0) atomicAdd(S + b * NN + nt * 16 + lg * 4 + r, vsum);
        }

    // ---------- PV: fat[n][dv] += att[n][m] * v[m][dv], m-steps of 32 ----------
    f32x4 accp[8][4];
#pragma unroll
    for (int nt = 0; nt < 8; nt++)
#pragma unroll
        for (int dt = 0; dt < 4; dt++) accp[nt][dt] = {0.f, 0.f, 0.f, 0.f};

    for (int ms = 0; ms < 4; ms++) {
        // stage v slab [32m][256dv] transposed into vt[dv][m] (stride 40 u16)
        if (bf) {
            const u32* vg = (const u32*)v + ((size_t)(b * MM + m0 + ms * 32)) * 128;
#pragma unroll
            for (int i = 0; i < 16; i++) {
                int fid = i * 256 + t;            // 4096 u32 items
                int mm = fid >> 7, du = fid & 127;
                u32 val = vg[(size_t)mm * 128 + du];
                vt[(du * 2 + 0) * 40 + mm] = (u16)(val & 0xffffu);
                vt[(du * 2 + 1) * 40 + mm] = (u16)(val >> 16);
            }
        } else {
            const float4* vg = (const float4*)v + ((size_t)(b * MM + m0 + ms * 32)) * 64;
#pragma unroll
            for (int i = 0; i < 8; i++) {
                int fid = i * 256 + t;            // 2048 float4 items
                int mm = fid >> 6, q4 = fid & 63;
                float4 f = vg[(size_t)mm * 64 + q4];
                vt[(q4 * 4 + 0) * 40 + mm] = f2b(f.x);
                vt[(q4 * 4 + 1) * 40 + mm] = f2b(f.y);
                vt[(q4 * 4 + 2) * 40 + mm] = f2b(f.z);
                vt[(q4 * 4 + 3) * 40 + mm] = f2b(f.w);
            }
        }
        __syncthreads();   // also guards first att reads vs att writes above
        short8 bfr[4];
#pragma unroll
        for (int dt = 0; dt < 4; dt++) {
            int dv = w * 64 + dt * 16 + ll;
            bfr[dt] = *(const short8*)(vt + dv * 40 + lg * 8);
        }
#pragma unroll
        for (int nt = 0; nt < 8; nt++) {
            int n = nt * 16 + ll;
            short8 af = *(const short8*)((char*)att + n * 256 + ((ms * 64 + lg * 16) ^ ((n & 7) << 4)));
#pragma unroll
            for (int dt = 0; dt < 4; dt++)
                accp[nt][dt] = __builtin_amdgcn_mfma_f32_16x16x32_bf16(af, bfr[dt], accp[nt][dt], 0, 0, 0);
        }
        __syncthreads();   // before next stage overwrites vt
    }

    float* fb = fat + ((size_t)b * NN) * DD;
#pragma unroll
    for (int nt = 0; nt < 8; nt++)
#pragma unroll
        for (int dt = 0; dt < 4; dt++)
#pragma unroll
            for (int r = 0; r < 4; r++) {
                int n = nt * 16 + lg * 4 + r;
                int dv = w * 64 + dt * 16 + ll;
                atomicAdd(fb + (size_t)n * DD + dv, accp[nt][dt][r]);
            }
}

// ---------------- K6: h = relu([snF, f_attn] @ Wf0T)  (8 rows/block, 4 cols/thread) ----------------
__global__ __launch_bounds__(256) void ffa(
    const float* __restrict__ snF, const float* __restrict__ fat, const float* __restrict__ S,
    const float* __restrict__ Wf0T, float* __restrict__ h)
{
    int rb = blockIdx.x;
    __shared__ float fi[8][512];
    __shared__ float rsh[8];
    if (TID < 8) rsh[TID] = 1.f / (S[rb * 8 + TID] + 1e-8f);
    __syncthreads();
    for (int idx = TID; idx < 4096; idx += 256) {
        int r = idx >> 9, dd = idx & 511;
        int bn = rb * 8 + r;
        fi[r][dd] = (dd < 256) ? snF[(size_t)bn * 256 + dd]
                               : fat[(size_t)bn * 256 + dd - 256] * rsh[r];
    }
    __syncthreads();
    float acc[8][4] = {};
    for (int d = 0; d < 512; d++) {
        float w0 = Wf0T[d * 1024 + TID];
        float w1 = Wf0T[d * 1024 + TID + 256];
        float w2 = Wf0T[d * 1024 + TID + 512];
        float w3 = Wf0T[d * 1024 + TID + 768];
#pragma unroll
        for (int r = 0; r < 8; r++) {
            float f = fi[r][d];
            acc[r][0] = fmaf(f, w0, acc[r][0]);
            acc[r][1] = fmaf(f, w1, acc[r][1]);
            acc[r][2] = fmaf(f, w2, acc[r][2]);
            acc[r][3] = fmaf(f, w3, acc[r][3]);
        }
    }
    for (int r = 0; r < 8; r++) {
        size_t base = (size_t)(rb * 8 + r) * 1024;
        h[base + TID] = fmaxf(acc[r][0], 0.f);
        h[base + TID + 256] = fmaxf(acc[r][1], 0.f);
        h[base + TID + 512] = fmaxf(acc[r][2], 0.f);
        h[base + TID + 768] = fmaxf(acc[r][3], 0.f);
    }
}

// ---------------- K7: gate + ff1 + output ----------------
__global__ __launch_bounds__(256) void ffb(
    const float* __restrict__ snA, const float* __restrict__ fat, const float* __restrict__ S,
    const float* __restrict__ WgT, const float* __restrict__ Wf1T,
    const float* __restrict__ h, void* __restrict__ out, const int* flagp)
{
    int rb = blockIdx.x;
    bool bf = (*flagp != 0);
    __shared__ float gi[8][512];
    __shared__ float hs[8][1024];
    __shared__ float rsh[8];
    if (TID < 8) rsh[TID] = 1.f / (S[rb * 8 + TID] + 1e-8f);
    __syncthreads();
    for (int idx = TID; idx < 4096; idx += 256) {
        int r = idx >> 9, dd = idx & 511;
        int bn = rb * 8 + r;
        gi[r][dd] = (dd < 256) ? snA[(size_t)bn * 256 + dd]
                               : fat[(size_t)bn * 256 + dd - 256] * rsh[r];
    }
    for (int idx = TID; idx < 8192; idx += 256) {
        int r = idx >> 10, dd = idx & 1023;
        hs[r][dd] = h[(size_t)(rb * 8 + r) * 1024 + dd];
    }
    __syncthreads();
    float ag[8] = {0, 0, 0, 0, 0, 0, 0, 0};
    float af[8] = {0, 0, 0, 0, 0, 0, 0, 0};
    for (int d = 0; d < 512; d++) {
        float w = WgT[d * 256 + TID];
#pragma unroll
        for (int r = 0; r < 8; r++) ag[r] = fmaf(gi[r][d], w, ag[r]);
    }
    for (int j = 0; j < 1024; j++) {
        float w = Wf1T[j * 256 + TID];
#pragma unroll
        for (int r = 0; r < 8; r++) af[r] = fmaf(hs[r][j], w, af[r]);
    }
    for (int r = 0; r < 8; r++) {
        int bn = rb * 8 + r;
        float fa = gi[r][256 + TID];
        float g = 1.f / (1.f + __expf(-ag[r]));
        float val = g * fa + af[r];
        if (bf) ((u16*)out)[(size_t)bn * 256 + TID] = f2b(val);
        else    ((float*)out)[(size_t)bn * 256 + TID] = val;
    }
}

// ---------------- launch ----------------
extern "C" void kernel_launch(void* const* d_in, const int* in_sizes, int n_in,
                              void* d_out, int out_size, void* d_ws, size_t ws_size,
                              hipStream_t stream)
{
    const void* in[32];
    bool sig_order = (n_in >= 1 && in_sizes[0] == 1);
    for (int i = 0; i < 32; i++) {
        int j = sig_order ? ((i < 28) ? (i + 4) : (i - 28)) : i;
        in[i] = d_in[j];
    }

    const void* qw0 = in[0];  const void* qb0 = in[1];
    const void* qw1 = in[2];  const void* qb1 = in[3];
    const void* qwp = in[4];  const void* qbp = in[5];
    const void* gw0 = in[6];  const void* gb0 = in[7];
    const void* gw1 = in[8];  const void* gb1 = in[9];
    const void* gwp = in[10]; const void* gbp = in[11];
    const void* f0w0 = in[12]; const void* f0b0 = in[13];
    const void* f0w1 = in[14]; const void* f0b1 = in[15];
    const void* f0wp = in[16]; const void* f0bp = in[17];
    const void* f1w0 = in[18]; const void* f1b0 = in[19];
    const void* f1w1 = in[20]; const void* f1b1 = in[21];
    const void* f1wp = in[22]; const void* f1bp = in[23];
    const void* lnAw = in[24]; const void* lnAb = in[25];
    const void* lnFw = in[26]; const void* lnFb = in[27];
    const void* t    = in[28]; const void* slots = in[29];
    const void* kk   = in[30]; const void* vv   = in[31];

    float* F = (float*)d_ws;
    int* flagp = (int*)(F + O_FLAG);

    // zero S + f_attn accumulators (contiguous region)
    hipMemsetAsync(F + O_S, 0, (size_t)(BN + BN * DD) * sizeof(float), stream);

    probe_dtype<<<1, 1, 0, stream>>>(lnAw, flagp);

    tdw_mlp<<<1, 256, 0, stream>>>(t, qw0, qb0, qw1, qb1, gw0, gb0, gw1, gb1,
                                   f0w0, f0b0, f0w1, f0b1, f1w0, f1b0, f1w1, f1b1,
                                   F + O_H2, flagp);

    tdw_proj<<<256, 256, 0, stream>>>(qwp, qbp, F + O_H2 + 0, F + O_WQT, 8, 256, flagp);
    tdw_proj<<<512, 256, 0, stream>>>(gwp, gbp, F + O_H2 + 64, F + O_WGT, 8, 512, flagp);
    tdw_proj<<<2048, 256, 0, stream>>>(f0wp, f0bp, F + O_H2 + 128, F + O_WF0T, 10, 512, flagp);
    tdw_proj<<<1024, 256, 0, stream>>>(f1wp, f1bp, F + O_H2 + 192, F + O_WF1T, 8, 1024, flagp);

    layernorm_k<<<BN, 256, 0, stream>>>(slots, lnAw, lnAb, lnFw, lnFb,
                                        F + O_SNA, F + O_SNF, flagp);

    qproj<<<BN / 8, 256, 0, stream>>>(F + O_SNA, F + O_WQT, (u16*)(F + O_Q));

    attn_mfma<<<dim3(MM / 128, BB), 256, 0, stream>>>((const u16*)(F + O_Q), kk, vv,
                                                      F + O_FAT, F + O_S, flagp);

    ffa<<<BN / 8, 256, 0, stream>>>(F + O_SNF, F + O_FAT, F + O_S, F + O_WF0T, F + O_H);

    ffb<<<BN / 8, 256, 0, stream>>>(F + O_SNA, F + O_FAT, F + O_S, F + O_WGT, F + O_WF1T,
                                    F + O_H, d_out, flagp);
}

// Round 2
// 1012.142 us; speedup vs baseline: 1.7103x; 1.1185x over previous
//
#include <hip/hip_runtime.h>
#include <hip/hip_bf16.h>
#include <cstdint>

typedef unsigned short u16;
typedef unsigned int u32;
typedef __attribute__((ext_vector_type(8))) short short8;   // 8 x bf16 (4 VGPRs)
typedef __attribute__((ext_vector_type(4))) float f32x4;    // MFMA accumulator

#define TID ((int)threadIdx.x)

// bf16 (as ushort bits) -> f32
__device__ __forceinline__ float b2f(u16 u) { return __uint_as_float(((u32)u) << 16); }
// f32 -> bf16 (RNE)
__device__ __forceinline__ u16 f2b(float f) {
    u32 u = __float_as_uint(f);
    u += 0x7fffu + ((u >> 16) & 1u);
    return (u16)(u >> 16);
}
__device__ __forceinline__ float2 upk(u32 u) {
    float2 r;
    r.x = __uint_as_float(u << 16);
    r.y = __uint_as_float(u & 0xffff0000u);
    return r;
}
__device__ __forceinline__ float silu_f(float x) { return x / (1.f + __expf(-x)); }

// dtype-adaptive scalar load (wave-uniform bf flag)
__device__ __forceinline__ float ldx(const void* p, size_t i, bool bf) {
    float v;
    if (bf) v = b2f(((const u16*)p)[i]);
    else    v = ((const float*)p)[i];
    return v;
}

// ---------------- constants ----------------
#define BB 32
#define NN 128
#define DD 256
#define MM 4096
#define HH 1024
#define BN (BB * NN)   // 4096 rows

// workspace layout (floats)
#define O_FLAG 0
#define O_H2   8
#define O_S    (O_H2 + 256)                // 264
#define O_FAT  (O_S + BN)                  // 4360
#define O_WQT  (O_FAT + BN * DD)
#define O_WGT  (O_WQT + 256 * 256)
#define O_WF0T (O_WGT + 512 * 256)
#define O_WF1T (O_WF0T + 512 * 1024)
#define O_SNA  (O_WF1T + 1024 * 256)
#define O_SNF  (O_SNA + BN * DD)
#define O_Q    (O_SNF + BN * DD)           // q as bf16 (u16)
#define O_H    (O_Q + BN * DD)
// fatP (32 x BN x DD fp32 = 134 MB) overlays [O_H, O_H + 32*BN*DD):
//   written by attn, read by reduce_fat, DEAD before ffa writes h at O_H.
#define O_FATP O_H
// total ws = O_H + 32*BN*DD floats ≈ 155 MB

// ---------------- K0: dtype probe ----------------
__global__ void probe_dtype(const void* lnAw, int* flag) {
    u32 bits = *(const u32*)lnAw;
    *flag = ((bits & 0xFFFFu) == 0x3F80u) ? 1 : 0;
}

// ---------------- K1: time-dependent tiny MLP (h2 for 4 heads) ----------------
__global__ __launch_bounds__(256) void tdw_mlp(
    const void* t,
    const void* qw0, const void* qb0, const void* qw1, const void* qb1,
    const void* gw0, const void* gb0, const void* gw1, const void* gb1,
    const void* f0w0, const void* f0b0, const void* f0w1, const void* f0b1,
    const void* f1w0, const void* f1b0, const void* f1w1, const void* f1b1,
    float* h2out, const int* flagp)
{
    __shared__ float emb[257];
    __shared__ float h1s[256];
    bool bf = (*flagp != 0);
    float tv = ldx(t, 0, bf);
    const float c = -9.210340371976184f / 128.f;  // -ln(10000)/N_FREQ
    for (int i = TID; i < 257; i += 256) {
        float val;
        if (i == 0) val = tv;
        else if (i <= 128) val = sinf(c * (float)(i - 1) * tv);
        else val = cosf(c * (float)(i - 129) * tv);
        emb[i] = val;
    }
    __syncthreads();
    int head = TID >> 6, o = TID & 63;
    const void* w0s[4] = {qw0, gw0, f0w0, f1w0};
    const void* b0s[4] = {qb0, gb0, f0b0, f1b0};
    const void* w1s[4] = {qw1, gw1, f0w1, f1w1};
    const void* b1s[4] = {qb1, gb1, f0b1, f1b1};
    float acc = ldx(b0s[head], o, bf);
    if (bf) {
        const u16* w0 = (const u16*)w0s[head];
        for (int j = 0; j < 257; j++) acc += b2f(w0[o * 257 + j]) * emb[j];
    } else {
        const float* w0 = (const float*)w0s[head];
        for (int j = 0; j < 257; j++) acc += w0[o * 257 + j] * emb[j];
    }
    h1s[TID] = silu_f(acc);
    __syncthreads();
    float acc2 = ldx(b1s[head], o, bf);
    if (bf) {
        const u16* w1 = (const u16*)w1s[head];
        for (int j = 0; j < 64; j++) acc2 += b2f(w1[o * 64 + j]) * h1s[head * 64 + j];
    } else {
        const float* w1 = (const float*)w1s[head];
        for (int j = 0; j < 64; j++) acc2 += w1[o * 64 + j] * h1s[head * 64 + j];
    }
    h2out[TID] = silu_f(acc2);
}

// ---------------- K2: W = wp @ h2 + bp, written TRANSPOSED: WT[d*dout+o] ----------------
__global__ __launch_bounds__(256) void tdw_proj(
    const void* __restrict__ wp, const void* __restrict__ bp,
    const float* __restrict__ h2, float* __restrict__ WT,
    int dout_shift, int din, const int* flagp)
{
    __shared__ float h2s[64];
    bool bf = (*flagp != 0);
    if (TID < 64) h2s[TID] = h2[TID];
    __syncthreads();
    int j = blockIdx.x * 256 + TID;          // j = d*dout + o (coalesced write)
    int d = j >> dout_shift;
    int o = j & ((1 << dout_shift) - 1);
    long i = (long)o * din + d;              // original row index
    float acc;
    if (bf) acc = b2f(((const u16*)bp)[i]);
    else    acc = ((const float*)bp)[i];
    if (bf) {
        const uint4* row = (const uint4*)((const u16*)wp + i * 64);
#pragma unroll
        for (int r = 0; r < 8; r++) {
            uint4 u = row[r];
            float2 p;
            p = upk(u.x); acc += p.x * h2s[r * 8 + 0] + p.y * h2s[r * 8 + 1];
            p = upk(u.y); acc += p.x * h2s[r * 8 + 2] + p.y * h2s[r * 8 + 3];
            p = upk(u.z); acc += p.x * h2s[r * 8 + 4] + p.y * h2s[r * 8 + 5];
            p = upk(u.w); acc += p.x * h2s[r * 8 + 6] + p.y * h2s[r * 8 + 7];
        }
    } else {
        const float4* row = (const float4*)((const float*)wp + i * 64);
#pragma unroll
        for (int r = 0; r < 16; r++) {
            float4 u = row[r];
            acc += u.x * h2s[r * 4 + 0] + u.y * h2s[r * 4 + 1]
                 + u.z * h2s[r * 4 + 2] + u.w * h2s[r * 4 + 3];
        }
    }
    WT[j] = acc;
}

// ---------------- K3: LayerNorm (both A and F affine variants) ----------------
__global__ __launch_bounds__(256) void layernorm_k(
    const void* __restrict__ slots,
    const void* lnAw, const void* lnAb, const void* lnFw, const void* lnFb,
    float* __restrict__ snA, float* __restrict__ snF, const int* flagp)
{
    int bn = blockIdx.x;
    bool bf = (*flagp != 0);
    float x;
    if (bf) x = b2f(((const u16*)slots)[(size_t)bn * DD + TID]);
    else    x = ((const float*)slots)[(size_t)bn * DD + TID];
    float s1 = x, s2 = x * x;
    for (int off = 32; off; off >>= 1) {
        s1 += __shfl_down(s1, off, 64);
        s2 += __shfl_down(s2, off, 64);
    }
    __shared__ float r1[4], r2[4];
    __shared__ float mu_s, rs_s;
    if ((TID & 63) == 0) { r1[TID >> 6] = s1; r2[TID >> 6] = s2; }
    __syncthreads();
    if (TID == 0) {
        float a = r1[0] + r1[1] + r1[2] + r1[3];
        float b = r2[0] + r2[1] + r2[2] + r2[3];
        float mu = a * (1.f / 256.f);
        float var = b * (1.f / 256.f) - mu * mu;
        mu_s = mu;
        rs_s = rsqrtf(var + 1e-5f);
    }
    __syncthreads();
    float xh = (x - mu_s) * rs_s;
    snA[(size_t)bn * DD + TID] = xh * ldx(lnAw, TID, bf) + ldx(lnAb, TID, bf);
    snF[(size_t)bn * DD + TID] = xh * ldx(lnFw, TID, bf) + ldx(lnFb, TID, bf);
}

// ---------------- K4: q = snA @ WqT, output bf16 (float4 LDS reads) ----------------
__global__ __launch_bounds__(256) void qproj(
    const float* __restrict__ snA, const float* __restrict__ WqT, u16* __restrict__ qb)
{
    int rb = blockIdx.x;
    __shared__ float sn[8][256];
    for (int idx = TID; idx < 512; idx += 256) {
        int r = idx >> 6, q4 = idx & 63;
        *(float4*)&sn[r][q4 * 4] = *(const float4*)(snA + (size_t)rb * 2048 + r * 256 + q4 * 4);
    }
    __syncthreads();
    float acc[8] = {0, 0, 0, 0, 0, 0, 0, 0};
    for (int d = 0; d < 256; d += 4) {
        float w0 = WqT[(d + 0) * 256 + TID];
        float w1 = WqT[(d + 1) * 256 + TID];
        float w2 = WqT[(d + 2) * 256 + TID];
        float w3 = WqT[(d + 3) * 256 + TID];
#pragma unroll
        for (int r = 0; r < 8; r++) {
            float4 s4 = *(const float4*)&sn[r][d];
            acc[r] = fmaf(s4.x, w0, fmaf(s4.y, w1, fmaf(s4.z, w2, fmaf(s4.w, w3, acc[r]))));
        }
    }
    for (int r = 0; r < 8; r++) qb[(size_t)(rb * 8 + r) * 256 + TID] = f2b(acc[r]);
}

// ---------------- K5: MFMA attention (partials, NO fat atomics) ----------------
// Block = (m-tile of 128 feats, batch b). 4 waves, 256 threads.
// Wave w owns 32 feat-columns [32w,32w+32) for QK+softmax, and dv-slice [64w,64w+64) for PV.
// PV result stored non-atomically to fatP[mtile][bn][dv]; reduced by reduce_fat.
__global__ __launch_bounds__(256, 2) void attn_mfma(
    const u16* __restrict__ qbG,       // [B*128][256] bf16
    const void* __restrict__ k, const void* __restrict__ v,
    float* __restrict__ fatP, float* __restrict__ S, const int* flagp)
{
    const int b = blockIdx.y;
    const int mt = blockIdx.x;
    const int m0 = mt * 128;
    const bool bf = (*flagp != 0);
    const int t = TID;
    const int l = t & 63, w = t >> 6;
    const int lg = l >> 4;       // lane group 0..3
    const int ll = l & 15;

    __shared__ alignas(16) u16 AB[128 * 128];   // 32 KB: qb(8K u16) + kb(8K u16), reused as att
    __shared__ alignas(16) u16 vt[256 * 40];    // 20 KB

    u16* qb = AB;            // [n][64]   byte = n*128 + (doff ^ ((n&7)<<4))
    u16* kb = AB + 8192;     // [mm][64]  byte = mm*128 + (doff ^ ((mm&7)<<4))

    f32x4 acc[2][8];
#pragma unroll
    for (int s = 0; s < 2; s++)
#pragma unroll
        for (int nt = 0; nt < 8; nt++) acc[s][nt] = {0.f, 0.f, 0.f, 0.f};

    // ---------- QK^T: acc[s][nt] = q[16nt..][d] . k[32w+16s..][d], d-chunks of 64 ----------
    for (int dc = 0; dc < 4; dc++) {
        {   // stage q chunk (bf16 source): 4096 u32
            const u32* qg = (const u32*)qbG + (size_t)b * 128 * 128 + dc * 32;
#pragma unroll
            for (int i = 0; i < 16; i++) {
                int fid = i * 256 + t;
                int n = fid >> 5, dp = fid & 31;
                u32 val = qg[n * 128 + dp];
                *(u32*)((char*)qb + n * 128 + ((dp * 4) ^ ((n & 7) << 4))) = val;
            }
        }
        if (bf) {   // stage k chunk, bf16 wire
            const u32* kg = (const u32*)k + ((size_t)(b * MM + m0)) * 128 + dc * 32;
#pragma unroll
            for (int i = 0; i < 16; i++) {
                int fid = i * 256 + t;
                int mm = fid >> 5, dp = fid & 31;
                u32 val = kg[(size_t)mm * 128 + dp];
                *(u32*)((char*)kb + mm * 128 + ((dp * 4) ^ ((mm & 7) << 4))) = val;
            }
        } else {    // fp32 wire: convert on the fly
            const float4* kg = (const float4*)k + ((size_t)(b * MM + m0)) * 64 + dc * 16;
#pragma unroll
            for (int i = 0; i < 8; i++) {
                int fid = i * 256 + t;
                int mm = fid >> 4, q4 = fid & 15;
                float4 f = kg[(size_t)mm * 64 + q4];
                u32 p0 = ((u32)f2b(f.x)) | ((u32)f2b(f.y) << 16);
                u32 p1 = ((u32)f2b(f.z)) | ((u32)f2b(f.w) << 16);
                char* base = (char*)kb + mm * 128;
                *(u32*)(base + (((q4 * 8) + 0) ^ ((mm & 7) << 4))) = p0;
                *(u32*)(base + (((q4 * 8) + 4) ^ ((mm & 7) << 4))) = p1;
            }
        }
        __syncthreads();
#pragma unroll
        for (int ds = 0; ds < 2; ds++) {
            int doff = ds * 64 + lg * 16;
            short8 bfr[2];
#pragma unroll
            for (int s = 0; s < 2; s++) {
                int mm = w * 32 + s * 16 + ll;
                bfr[s] = *(const short8*)((char*)kb + mm * 128 + (doff ^ ((mm & 7) << 4)));
            }
#pragma unroll
            for (int nt = 0; nt < 8; nt++) {
                int n = nt * 16 + ll;
                short8 af = *(const short8*)((char*)qb + n * 128 + (doff ^ ((n & 7) << 4)));
                acc[0][nt] = __builtin_amdgcn_mfma_f32_16x16x32_bf16(af, bfr[0], acc[0][nt], 0, 0, 0);
                acc[1][nt] = __builtin_amdgcn_mfma_f32_16x16x32_bf16(af, bfr[1], acc[1][nt], 0, 0, 0);
            }
        }
        __syncthreads();
    }

    // ---------- softmax over slots (n), per column m; fully in-register ----------
    const float scale = 0.0625f;
#pragma unroll
    for (int s = 0; s < 2; s++) {
        float cm = -1e30f;
#pragma unroll
        for (int nt = 0; nt < 8; nt++)
#pragma unroll
            for (int r = 0; r < 4; r++) cm = fmaxf(cm, acc[s][nt][r]);
        cm = fmaxf(cm, __shfl_xor(cm, 16));
        cm = fmaxf(cm, __shfl_xor(cm, 32));
        float cs = 0.f;
#pragma unroll
        for (int nt = 0; nt < 8; nt++)
#pragma unroll
            for (int r = 0; r < 4; r++) {
                float ev = __expf((acc[s][nt][r] - cm) * scale);
                acc[s][nt][r] = ev;
                cs += ev;
            }
        cs += __shfl_xor(cs, 16);
        cs += __shfl_xor(cs, 32);
        float inv = 1.f / cs;
#pragma unroll
        for (int nt = 0; nt < 8; nt++)
#pragma unroll
            for (int r = 0; r < 4; r++) acc[s][nt][r] *= inv;
    }

    // ---------- att -> LDS (bf16, swizzled) + S row-sum partials ----------
    u16* att = AB;   // [n][128] byte = n*256 + ((mw*2) ^ ((n&7)<<4))
#pragma unroll
    for (int s = 0; s < 2; s++)
#pragma unroll
        for (int nt = 0; nt < 8; nt++)
#pragma unroll
            for (int r = 0; r < 4; r++) {
                int n = nt * 16 + lg * 4 + r;
                int mw = w * 32 + s * 16 + ll;
                *(u16*)((char*)att + n * 256 + ((mw * 2) ^ ((n & 7) << 4))) = f2b(acc[s][nt][r]);
            }
    // S[n] += sum over this block's 128 feats (butterfly over the 16 ll-lanes)
#pragma unroll
    for (int nt = 0; nt < 8; nt++)
#pragma unroll
        for (int r = 0; r < 4; r++) {
            float vsum = acc[0][nt][r] + acc[1][nt][r];
            vsum += __shfl_xor(vsum, 1);
            vsum += __shfl_xor(vsum, 2);
            vsum += __shfl_xor(vsum, 4);
            vsum += __shfl_xor(vsum, 8);
            if (ll == 0) atomicAdd(S + b * NN + nt * 16 + lg * 4 + r, vsum);
        }

    // ---------- PV: accp[n][dv] = sum over this tile's 128 m, m-steps of 32 ----------
    f32x4 accp[8][4];
#pragma unroll
    for (int nt = 0; nt < 8; nt++)
#pragma unroll
        for (int dt = 0; dt < 4; dt++) accp[nt][dt] = {0.f, 0.f, 0.f, 0.f};

    for (int ms = 0; ms < 4; ms++) {
        // stage v slab [32m][256dv] transposed into vt[dv][m] (stride 40 u16)
        if (bf) {
            const u32* vg = (const u32*)v + ((size_t)(b * MM + m0 + ms * 32)) * 128;
#pragma unroll
            for (int i = 0; i < 16; i++) {
                int fid = i * 256 + t;            // 4096 u32 items
                int mm = fid >> 7, du = fid & 127;
                u32 val = vg[(size_t)mm * 128 + du];
                vt[(du * 2 + 0) * 40 + mm] = (u16)(val & 0xffffu);
                vt[(du * 2 + 1) * 40 + mm] = (u16)(val >> 16);
            }
        } else {
            const float4* vg = (const float4*)v + ((size_t)(b * MM + m0 + ms * 32)) * 64;
#pragma unroll
            for (int i = 0; i < 8; i++) {
                int fid = i * 256 + t;            // 2048 float4 items
                int mm = fid >> 6, q4 = fid & 63;
                float4 f = vg[(size_t)mm * 64 + q4];
                vt[(q4 * 4 + 0) * 40 + mm] = f2b(f.x);
                vt[(q4 * 4 + 1) * 40 + mm] = f2b(f.y);
                vt[(q4 * 4 + 2) * 40 + mm] = f2b(f.z);
                vt[(q4 * 4 + 3) * 40 + mm] = f2b(f.w);
            }
        }
        __syncthreads();   // also guards first att reads vs att writes above
        short8 bfr[4];
#pragma unroll
        for (int dt = 0; dt < 4; dt++) {
            int dv = w * 64 + dt * 16 + ll;
            bfr[dt] = *(const short8*)(vt + dv * 40 + lg * 8);
        }
#pragma unroll
        for (int nt = 0; nt < 8; nt++) {
            int n = nt * 16 + ll;
            short8 af = *(const short8*)((char*)att + n * 256 + ((ms * 64 + lg * 16) ^ ((n & 7) << 4)));
#pragma unroll
            for (int dt = 0; dt < 4; dt++)
                accp[nt][dt] = __builtin_amdgcn_mfma_f32_16x16x32_bf16(af, bfr[dt], accp[nt][dt], 0, 0, 0);
        }
        __syncthreads();   // before next stage overwrites vt
    }

    // ---------- plain stores to fatP[mt][bn][dv] (no atomics) ----------
    float* fp = fatP + ((size_t)mt * BN + (size_t)b * NN) * DD;
#pragma unroll
    for (int nt = 0; nt < 8; nt++)
#pragma unroll
        for (int dt = 0; dt < 4; dt++)
#pragma unroll
            for (int r = 0; r < 4; r++) {
                int n = nt * 16 + lg * 4 + r;
                int dv = w * 64 + dt * 16 + ll;
                fp[(size_t)n * DD + dv] = accp[nt][dt][r];
            }
}

// ---------------- K5b: reduce fatP over the 32 m-tiles ----------------
__global__ __launch_bounds__(256) void reduce_fat(
    const float* __restrict__ fatP, float* __restrict__ fat)
{
    size_t i = ((size_t)blockIdx.x * 256 + TID) * 4;
    float4 a = *(const float4*)(fatP + i);
#pragma unroll
    for (int mt = 1; mt < 32; mt++) {
        float4 bb = *(const float4*)(fatP + (size_t)mt * (size_t)BN * DD + i);
        a.x += bb.x; a.y += bb.y; a.z += bb.z; a.w += bb.w;
    }
    *(float4*)(fat + i) = a;
}

// ---------------- K6: h = relu([snF, f_attn] @ Wf0T)  (float4 LDS reads) ----------------
__global__ __launch_bounds__(256) void ffa(
    const float* __restrict__ snF, const float* __restrict__ fat, const float* __restrict__ S,
    const float* __restrict__ Wf0T, float* __restrict__ h)
{
    int rb = blockIdx.x;
    __shared__ float fi[8][512];
    __shared__ float rsh[8];
    if (TID < 8) rsh[TID] = 1.f / (S[rb * 8 + TID] + 1e-8f);
    __syncthreads();
    for (int idx = TID; idx < 1024; idx += 256) {
        int r = idx >> 7, q4 = idx & 127;
        size_t bn = (size_t)rb * 8 + r;
        float4 val;
        if (q4 < 64) val = *(const float4*)(snF + bn * 256 + q4 * 4);
        else {
            val = *(const float4*)(fat + bn * 256 + (q4 - 64) * 4);
            float s = rsh[r];
            val.x *= s; val.y *= s; val.z *= s; val.w *= s;
        }
        *(float4*)&fi[r][q4 * 4] = val;
    }
    __syncthreads();
    float acc[8][4] = {};
    for (int d = 0; d < 512; d += 4) {
        float w[4][4];
#pragma unroll
        for (int kk2 = 0; kk2 < 4; kk2++) {
            const float* wp_ = Wf0T + (size_t)(d + kk2) * 1024 + TID;
            w[kk2][0] = wp_[0];   w[kk2][1] = wp_[256];
            w[kk2][2] = wp_[512]; w[kk2][3] = wp_[768];
        }
#pragma unroll
        for (int r = 0; r < 8; r++) {
            float4 f = *(const float4*)&fi[r][d];
            float fv[4] = {f.x, f.y, f.z, f.w};
#pragma unroll
            for (int kk2 = 0; kk2 < 4; kk2++)
#pragma unroll
                for (int c = 0; c < 4; c++)
                    acc[r][c] = fmaf(fv[kk2], w[kk2][c], acc[r][c]);
        }
    }
    for (int r = 0; r < 8; r++) {
        size_t base = (size_t)(rb * 8 + r) * 1024;
        h[base + TID] = fmaxf(acc[r][0], 0.f);
        h[base + TID + 256] = fmaxf(acc[r][1], 0.f);
        h[base + TID + 512] = fmaxf(acc[r][2], 0.f);
        h[base + TID + 768] = fmaxf(acc[r][3], 0.f);
    }
}

// ---------------- K7: gate + ff1 + output (float4 LDS reads) ----------------
__global__ __launch_bounds__(256) void ffb(
    const float* __restrict__ snA, const float* __restrict__ fat, const float* __restrict__ S,
    const float* __restrict__ WgT, const float* __restrict__ Wf1T,
    const float* __restrict__ h, void* __restrict__ out, const int* flagp)
{
    int rb = blockIdx.x;
    bool bf = (*flagp != 0);
    __shared__ float gi[8][512];
    __shared__ float hs[8][1024];
    __shared__ float rsh[8];
    if (TID < 8) rsh[TID] = 1.f / (S[rb * 8 + TID] + 1e-8f);
    __syncthreads();
    for (int idx = TID; idx < 1024; idx += 256) {
        int r = idx >> 7, q4 = idx & 127;
        size_t bn = (size_t)rb * 8 + r;
        float4 val;
        if (q4 < 64) val = *(const float4*)(snA + bn * 256 + q4 * 4);
        else {
            val = *(const float4*)(fat + bn * 256 + (q4 - 64) * 4);
            float s = rsh[r];
            val.x *= s; val.y *= s; val.z *= s; val.w *= s;
        }
        *(float4*)&gi[r][q4 * 4] = val;
    }
    for (int idx = TID; idx < 2048; idx += 256) {
        int r = idx >> 8, q4 = idx & 255;
        *(float4*)&hs[r][q4 * 4] = *(const float4*)(h + (size_t)(rb * 8 + r) * 1024 + q4 * 4);
    }
    __syncthreads();
    float ag[8] = {0, 0, 0, 0, 0, 0, 0, 0};
    float af[8] = {0, 0, 0, 0, 0, 0, 0, 0};
    for (int d = 0; d < 512; d += 4) {
        float w0 = WgT[(d + 0) * 256 + TID];
        float w1 = WgT[(d + 1) * 256 + TID];
        float w2 = WgT[(d + 2) * 256 + TID];
        float w3 = WgT[(d + 3) * 256 + TID];
#pragma unroll
        for (int r = 0; r < 8; r++) {
            float4 g = *(const float4*)&gi[r][d];
            ag[r] = fmaf(g.x, w0, fmaf(g.y, w1, fmaf(g.z, w2, fmaf(g.w, w3, ag[r]))));
        }
    }
    for (int j = 0; j < 1024; j += 4) {
        float w0 = Wf1T[(j + 0) * 256 + TID];
        float w1 = Wf1T[(j + 1) * 256 + TID];
        float w2 = Wf1T[(j + 2) * 256 + TID];
        float w3 = Wf1T[(j + 3) * 256 + TID];
#pragma unroll
        for (int r = 0; r < 8; r++) {
            float4 hv = *(const float4*)&hs[r][j];
            af[r] = fmaf(hv.x, w0, fmaf(hv.y, w1, fmaf(hv.z, w2, fmaf(hv.w, w3, af[r]))));
        }
    }
    for (int r = 0; r < 8; r++) {
        int bn = rb * 8 + r;
        float fa = gi[r][256 + TID];
        float g = 1.f / (1.f + __expf(-ag[r]));
        float val = g * fa + af[r];
        if (bf) ((u16*)out)[(size_t)bn * 256 + TID] = f2b(val);
        else    ((float*)out)[(size_t)bn * 256 + TID] = val;
    }
}

// ---------------- launch ----------------
extern "C" void kernel_launch(void* const* d_in, const int* in_sizes, int n_in,
                              void* d_out, int out_size, void* d_ws, size_t ws_size,
                              hipStream_t stream)
{
    const void* in[32];
    bool sig_order = (n_in >= 1 && in_sizes[0] == 1);
    for (int i = 0; i < 32; i++) {
        int j = sig_order ? ((i < 28) ? (i + 4) : (i - 28)) : i;
        in[i] = d_in[j];
    }

    const void* qw0 = in[0];  const void* qb0 = in[1];
    const void* qw1 = in[2];  const void* qb1 = in[3];
    const void* qwp = in[4];  const void* qbp = in[5];
    const void* gw0 = in[6];  const void* gb0 = in[7];
    const void* gw1 = in[8];  const void* gb1 = in[9];
    const void* gwp = in[10]; const void* gbp = in[11];
    const void* f0w0 = in[12]; const void* f0b0 = in[13];
    const void* f0w1 = in[14]; const void* f0b1 = in[15];
    const void* f0wp = in[16]; const void* f0bp = in[17];
    const void* f1w0 = in[18]; const void* f1b0 = in[19];
    const void* f1w1 = in[20]; const void* f1b1 = in[21];
    const void* f1wp = in[22]; const void* f1bp = in[23];
    const void* lnAw = in[24]; const void* lnAb = in[25];
    const void* lnFw = in[26]; const void* lnFb = in[27];
    const void* t    = in[28]; const void* slots = in[29];
    const void* kk   = in[30]; const void* vv   = in[31];

    float* F = (float*)d_ws;
    int* flagp = (int*)(F + O_FLAG);

    // zero S accumulator only (fat fully written by reduce_fat; fatP fully written by attn)
    hipMemsetAsync(F + O_S, 0, (size_t)BN * sizeof(float), stream);

    probe_dtype<<<1, 1, 0, stream>>>(lnAw, flagp);

    tdw_mlp<<<1, 256, 0, stream>>>(t, qw0, qb0, qw1, qb1, gw0, gb0, gw1, gb1,
                                   f0w0, f0b0, f0w1, f0b1, f1w0, f1b0, f1w1, f1b1,
                                   F + O_H2, flagp);

    tdw_proj<<<256, 256, 0, stream>>>(qwp, qbp, F + O_H2 + 0, F + O_WQT, 8, 256, flagp);
    tdw_proj<<<512, 256, 0, stream>>>(gwp, gbp, F + O_H2 + 64, F + O_WGT, 8, 512, flagp);
    tdw_proj<<<2048, 256, 0, stream>>>(f0wp, f0bp, F + O_H2 + 128, F + O_WF0T, 10, 512, flagp);
    tdw_proj<<<1024, 256, 0, stream>>>(f1wp, f1bp, F + O_H2 + 192, F + O_WF1T, 8, 1024, flagp);

    layernorm_k<<<BN, 256, 0, stream>>>(slots, lnAw, lnAb, lnFw, lnFb,
                                        F + O_SNA, F + O_SNF, flagp);

    qproj<<<BN / 8, 256, 0, stream>>>(F + O_SNA, F + O_WQT, (u16*)(F + O_Q));

    attn_mfma<<<dim3(MM / 128, BB), 256, 0, stream>>>((const u16*)(F + O_Q), kk, vv,
                                                      F + O_FATP, F + O_S, flagp);

    reduce_fat<<<BN * DD / 1024, 256, 0, stream>>>(F + O_FATP, F + O_FAT);

    ffa<<<BN / 8, 256, 0, stream>>>(F + O_SNF, F + O_FAT, F + O_S, F + O_WF0T, F + O_H);

    ffb<<<BN / 8, 256, 0, stream>>>(F + O_SNA, F + O_FAT, F + O_S, F + O_WGT, F + O_WF1T,
                                    F + O_H, d_out, flagp);
}